// Round 1
// baseline (375.389 us; speedup 1.0000x reference)
//
#include <hip/hip_runtime.h>

#define B_    8
#define T_    512
#define D_    768
#define L_    16
#define DL_   128
#define NO_   4096   // L_*DL_*2
#define M_    4096   // B_*T_
#define BN_EPS 1e-5f

typedef __attribute__((ext_vector_type(8))) short short8;
typedef __attribute__((ext_vector_type(4))) float f32x4;

__device__ inline unsigned short f2bf(float x) {
    unsigned int u = __float_as_uint(x);
    unsigned int r = (u + 0x7fffu + ((u >> 16) & 1u)) >> 16;
    return (unsigned short)r;
}

// ---------------- Kernel 1: masked per-channel sum / sumsq / count ----------
// grid 64 x 256. stats layout (floats): [0..767]=sum, [768..1535]=sumsq,
// [1536]=cnt, [2048..2815]=scale, [2816..3583]=shift
__global__ void k_stats(const float* __restrict__ f, const int* __restrict__ mask,
                        float* __restrict__ stats) {
    int tid = threadIdx.x;
    int t0  = blockIdx.x * 64;
    float s0 = 0.f, s1 = 0.f, s2 = 0.f, q0 = 0.f, q1 = 0.f, q2 = 0.f;
    for (int tt = 0; tt < 64; ++tt) {
        int t = t0 + tt;
        float m = mask[t] ? 1.f : 0.f;
        const float* row = f + (size_t)t * D_;
        float x0 = row[tid];
        float x1 = row[tid + 256];
        float x2 = row[tid + 512];
        s0 += x0 * m; q0 += x0 * x0 * m;
        s1 += x1 * m; q1 += x1 * x1 * m;
        s2 += x2 * m; q2 += x2 * x2 * m;
    }
    atomicAdd(&stats[tid      ], s0);
    atomicAdd(&stats[tid + 256], s1);
    atomicAdd(&stats[tid + 512], s2);
    atomicAdd(&stats[768 + tid      ], q0);
    atomicAdd(&stats[768 + tid + 256], q1);
    atomicAdd(&stats[768 + tid + 512], q2);
    if (tid == 0) {
        int c = 0;
        for (int tt = 0; tt < 64; ++tt) c += (mask[t0 + tt] ? 1 : 0);
        atomicAdd(&stats[1536], (float)c);
    }
}

// ---------------- Kernel 1b: finalize scale/shift ---------------------------
__global__ void k_finalize(const float* __restrict__ gamma, const float* __restrict__ beta,
                           float* __restrict__ stats) {
    int d = threadIdx.x;  // 768
    float denom = fmaxf(stats[1536], 1.f);
    float mean  = stats[d] / denom;
    float var   = fmaxf(stats[768 + d] / denom - mean * mean, 0.f);
    float sc    = gamma[d] * rsqrtf(var + BN_EPS);
    stats[2048 + d] = sc;
    stats[2816 + d] = beta[d] - mean * sc;
}

// ---------------- Kernel 2: normalize + mask + cast to bf16 -----------------
// grid 3072 x 256, one float4 per thread over M_*D_/4 = 786432
__global__ void k_norm(const float4* __restrict__ f4, const int* __restrict__ mask,
                       const float* __restrict__ stats, unsigned short* __restrict__ outp) {
    int i  = blockIdx.x * 256 + threadIdx.x;
    int d4 = i % (D_ / 4);
    int t  = i / (D_ / 4);
    float m = mask[t] ? 1.f : 0.f;
    float4 v = f4[i];
    int d = d4 * 4;
    float r0 = (v.x * stats[2048 + d + 0] + stats[2816 + d + 0]) * m;
    float r1 = (v.y * stats[2048 + d + 1] + stats[2816 + d + 1]) * m;
    float r2 = (v.z * stats[2048 + d + 2] + stats[2816 + d + 2]) * m;
    float r3 = (v.w * stats[2048 + d + 3] + stats[2816 + d + 3]) * m;
    ushort4 o;
    o.x = f2bf(r0); o.y = f2bf(r1); o.z = f2bf(r2); o.w = f2bf(r3);
    ((ushort4*)outp)[i] = o;
}

// ---------------- Kernel 2b: cast ff_w to bf16 ------------------------------
__global__ void k_castw(const float4* __restrict__ w4, unsigned short* __restrict__ outp) {
    int i = blockIdx.x * 256 + threadIdx.x;  // 786432 total
    float4 v = w4[i];
    ushort4 o;
    o.x = f2bf(v.x); o.y = f2bf(v.y); o.z = f2bf(v.z); o.w = f2bf(v.w);
    ((ushort4*)outp)[i] = o;
}

// ---------------- Kernel 3: FFN GEMM (h = relu(feats @ W^T + b)) ------------
// A[M_=4096][K=768] bf16, W[NO_=4096][K=768] bf16 (B^T pattern).
// 128x128 tile per 256-thread block; epilogue scatters into start/end arrays
// with layout [B][L][T][DL] bf16 each.
__launch_bounds__(256)
__global__ void k_ffn(const unsigned short* __restrict__ A, const unsigned short* __restrict__ W,
                      const float* __restrict__ bias,
                      unsigned short* __restrict__ startp, unsigned short* __restrict__ endp) {
    __shared__ alignas(16) unsigned short As[128][40];
    __shared__ alignas(16) unsigned short Bs[128][40];
    int tid  = threadIdx.x;
    int bm   = blockIdx.x, bn = blockIdx.y;
    int wave = tid >> 6, lane = tid & 63;
    int wm = wave >> 1, wn = wave & 1;
    int lr = lane & 15, quad = lane >> 4;
    f32x4 acc[4][4] = {};
    const int K = D_;
    for (int k0 = 0; k0 < K; k0 += 32) {
#pragma unroll
        for (int p = 0; p < 2; ++p) {
            int c   = tid + p * 256;
            int row = c >> 2, seg = c & 3;
            uint4 va = *(const uint4*)(A + ((size_t)(bm * 128 + row) * K + k0 + seg * 8));
            *(uint4*)&As[row][seg * 8] = va;
            uint4 vb = *(const uint4*)(W + ((size_t)(bn * 128 + row) * K + k0 + seg * 8));
            *(uint4*)&Bs[row][seg * 8] = vb;
        }
        __syncthreads();
        short8 a[4], b[4];
#pragma unroll
        for (int i = 0; i < 4; ++i) a[i] = *(const short8*)&As[wm * 64 + i * 16 + lr][quad * 8];
#pragma unroll
        for (int i = 0; i < 4; ++i) b[i] = *(const short8*)&Bs[wn * 64 + i * 16 + lr][quad * 8];
#pragma unroll
        for (int i = 0; i < 4; ++i)
#pragma unroll
            for (int j = 0; j < 4; ++j)
                acc[i][j] = __builtin_amdgcn_mfma_f32_16x16x32_bf16(a[i], b[j], acc[i][j], 0, 0, 0);
        __syncthreads();
    }
#pragma unroll
    for (int i = 0; i < 4; ++i) {
#pragma unroll
        for (int j = 0; j < 4; ++j) {
            int col  = bn * 128 + wn * 64 + j * 16 + lr;   // output channel o
            int l    = col >> 8;
            int dd   = (col >> 1) & 127;
            int cbit = col & 1;
            unsigned short* dst = cbit ? endp : startp;
            float bv = bias[col];
#pragma unroll
            for (int r = 0; r < 4; ++r) {
                int row = bm * 128 + wm * 64 + i * 16 + quad * 4 + r;  // token
                float v = acc[i][j][r] + bv;
                v = fmaxf(v, 0.f);
                int bb = row >> 9, tt = row & 511;
                dst[(((size_t)(bb * 16 + l) * 512 + tt) << 7) + dd] = f2bf(v);
            }
        }
    }
}

// ---------------- Kernel 4: biaffine scores ---------------------------------
// per (b,l): C[s,e] = sum_d start[s,d]*end[e,d] + label_bias[l]
// grid (4,4,128), block 256
__launch_bounds__(256)
__global__ void k_biaffine(const unsigned short* __restrict__ startp,
                           const unsigned short* __restrict__ endp,
                           const float* __restrict__ lbias, float* __restrict__ out) {
    __shared__ alignas(16) unsigned short As[128][40];
    __shared__ alignas(16) unsigned short Bs[128][40];
    int tid = threadIdx.x;
    int bm = blockIdx.x, bn = blockIdx.y;
    int bl = blockIdx.z;  // b*16 + l
    const unsigned short* A  = startp + (size_t)bl * 512 * 128;
    const unsigned short* Bp = endp   + (size_t)bl * 512 * 128;
    int wave = tid >> 6, lane = tid & 63;
    int wm = wave >> 1, wn = wave & 1;
    int lr = lane & 15, quad = lane >> 4;
    f32x4 acc[4][4] = {};
    const int K = DL_;
    for (int k0 = 0; k0 < K; k0 += 32) {
#pragma unroll
        for (int p = 0; p < 2; ++p) {
            int c   = tid + p * 256;
            int row = c >> 2, seg = c & 3;
            uint4 va = *(const uint4*)(A  + ((size_t)(bm * 128 + row) * K + k0 + seg * 8));
            *(uint4*)&As[row][seg * 8] = va;
            uint4 vb = *(const uint4*)(Bp + ((size_t)(bn * 128 + row) * K + k0 + seg * 8));
            *(uint4*)&Bs[row][seg * 8] = vb;
        }
        __syncthreads();
        short8 a[4], b[4];
#pragma unroll
        for (int i = 0; i < 4; ++i) a[i] = *(const short8*)&As[wm * 64 + i * 16 + lr][quad * 8];
#pragma unroll
        for (int i = 0; i < 4; ++i) b[i] = *(const short8*)&Bs[wn * 64 + i * 16 + lr][quad * 8];
#pragma unroll
        for (int i = 0; i < 4; ++i)
#pragma unroll
            for (int j = 0; j < 4; ++j)
                acc[i][j] = __builtin_amdgcn_mfma_f32_16x16x32_bf16(a[i], b[j], acc[i][j], 0, 0, 0);
        __syncthreads();
    }
    float lb = lbias[bl & 15];
    float* obase = out + (size_t)bl * 512 * 512;
#pragma unroll
    for (int i = 0; i < 4; ++i) {
#pragma unroll
        for (int j = 0; j < 4; ++j) {
            int e = bn * 128 + wn * 64 + j * 16 + lr;
#pragma unroll
            for (int r = 0; r < 4; ++r) {
                int s = bm * 128 + wm * 64 + i * 16 + quad * 4 + r;
                obase[(size_t)s * 512 + e] = acc[i][j][r] + lb;
            }
        }
    }
}

// ---------------- Kernel 5: spans_mask --------------------------------------
// out1[b,l,s,e] = (s<=e) && mask[b,s] && mask[b,e], written as 1.0f/0.0f.
// one thread per (b,s,e4); loops over all 16 l planes. grid 2048 x 256.
__global__ void k_mask(const int* __restrict__ mask, float* __restrict__ out1) {
    int idx = blockIdx.x * 256 + threadIdx.x;  // B_*T_*T_/4 = 524288
    int e4 = idx & 127;
    int s  = (idx >> 7) & 511;
    int b  = idx >> 16;
    int e0 = e4 * 4;
    float ms = mask[b * 512 + s] ? 1.f : 0.f;
    float4 v;
    v.x = (s <= e0 + 0 && mask[b * 512 + e0 + 0]) ? ms : 0.f;
    v.y = (s <= e0 + 1 && mask[b * 512 + e0 + 1]) ? ms : 0.f;
    v.z = (s <= e0 + 2 && mask[b * 512 + e0 + 2]) ? ms : 0.f;
    v.w = (s <= e0 + 3 && mask[b * 512 + e0 + 3]) ? ms : 0.f;
#pragma unroll
    for (int l = 0; l < 16; ++l) {
        ((float4*)out1)[((size_t)((b * 16 + l) * 512 + s) * 512 + e0) >> 2] = v;
    }
}

extern "C" void kernel_launch(void* const* d_in, const int* in_sizes, int n_in,
                              void* d_out, int out_size, void* d_ws, size_t ws_size,
                              hipStream_t stream) {
    const float* features = (const float*)d_in[0];
    const int*   mask     = (const int*)d_in[1];
    const float* gamma    = (const float*)d_in[2];
    const float* beta     = (const float*)d_in[3];
    const float* ffw      = (const float*)d_in[4];
    const float* ffb      = (const float*)d_in[5];
    const float* lbias    = (const float*)d_in[6];

    float* out_scores = (float*)d_out;
    float* out_mask   = out_scores + (size_t)B_ * L_ * T_ * T_;  // 33554432

    char* ws = (char*)d_ws;
    float*          stats  = (float*)ws;                              // 16 KiB
    unsigned short* feats  = (unsigned short*)(ws + 16384);           // 6 MiB
    unsigned short* wbf    = (unsigned short*)(ws + 16384 + 6291456); // 6 MiB
    unsigned short* startp = (unsigned short*)(ws + 12599296);        // 16 MiB
    unsigned short* endp   = (unsigned short*)(ws + 29376512);        // 16 MiB

    hipMemsetAsync(ws, 0, 16384, stream);
    k_stats<<<64, 256, 0, stream>>>(features, mask, stats);
    k_finalize<<<1, 768, 0, stream>>>(gamma, beta, stats);
    k_norm<<<3072, 256, 0, stream>>>((const float4*)features, mask, stats, feats);
    k_castw<<<3072, 256, 0, stream>>>((const float4*)ffw, wbf);
    dim3 g1(32, 32);
    k_ffn<<<g1, 256, 0, stream>>>(feats, wbf, ffb, startp, endp);
    dim3 g2(4, 4, 128);
    k_biaffine<<<g2, 256, 0, stream>>>(startp, endp, lbias, out_scores);
    k_mask<<<2048, 256, 0, stream>>>(mask, out_mask);
}